// Round 2
// baseline (341.997 us; speedup 1.0000x reference)
//
#include <hip/hip_runtime.h>
#include <stdint.h>

#define B_    4
#define N_    2048
#define D_    4096
#define E_    64
#define TOKENS (B_ * N_)        // 8192
#define KT    32                // K-tile staged in LDS
#define TM    64                // tokens per block tile

// ---------------------------------------------------------------------------
// K1: split-K fp32 GEMM. logits_partial[kc][tok][e] = A[tok,:]@W[:,e] (chunk).
// 256 threads, tile 64 tok x 64 experts, thread tile 4x4.
// As[kk][tok] pitch 68 (16B-aligned rows, breaks pow2 bank stride);
// Ws[kk][e]   pitch 68 (kills the 4-way write conflict of pitch 64).
// ---------------------------------------------------------------------------
__global__ __launch_bounds__(256) void k_gemm(const float* __restrict__ A,
                                              const float* __restrict__ W,
                                              float* __restrict__ P,
                                              int kchunk) {
    __shared__ float As[KT][TM + 4];
    __shared__ float Ws[KT][E_ + 4];

    const int tid   = threadIdx.x;
    const int tok0  = blockIdx.x * TM;
    const int kbase = blockIdx.y * kchunk;

    const int t0 = (tid >> 4) * 4;       // token offset 0..60
    const int e0 = (tid & 15) * 4;       // expert offset 0..60

    const int a_kf = (tid & 7) * 4;      // k offset for A stage
    const int a_t  = tid >> 3;           // 0..31
    const int w_e  = (tid & 15) * 4;
    const int w_k  = tid >> 4;           // 0..15

    float acc[4][4] = {{0.f}};

    for (int kt = 0; kt < kchunk; kt += KT) {
        const float* gA = A + (size_t)tok0 * D_ + (size_t)(kbase + kt);
        #pragma unroll
        for (int it = 0; it < 2; ++it) {
            const int tok = a_t + it * 32;
            const float4 v = *reinterpret_cast<const float4*>(
                gA + (size_t)tok * D_ + a_kf);
            As[a_kf + 0][tok] = v.x;
            As[a_kf + 1][tok] = v.y;
            As[a_kf + 2][tok] = v.z;
            As[a_kf + 3][tok] = v.w;
        }
        const float* gW = W + (size_t)(kbase + kt) * E_;
        #pragma unroll
        for (int it = 0; it < 2; ++it) {
            const int kk = w_k + it * 16;
            const float4 v = *reinterpret_cast<const float4*>(gW + kk * E_ + w_e);
            *reinterpret_cast<float4*>(&Ws[kk][w_e]) = v;
        }
        __syncthreads();

        #pragma unroll
        for (int kk = 0; kk < KT; ++kk) {
            const float4 a = *reinterpret_cast<const float4*>(&As[kk][t0]);
            const float4 b = *reinterpret_cast<const float4*>(&Ws[kk][e0]);
            acc[0][0] += a.x * b.x; acc[0][1] += a.x * b.y;
            acc[0][2] += a.x * b.z; acc[0][3] += a.x * b.w;
            acc[1][0] += a.y * b.x; acc[1][1] += a.y * b.y;
            acc[1][2] += a.y * b.z; acc[1][3] += a.y * b.w;
            acc[2][0] += a.z * b.x; acc[2][1] += a.z * b.y;
            acc[2][2] += a.z * b.z; acc[2][3] += a.z * b.w;
            acc[3][0] += a.w * b.x; acc[3][1] += a.w * b.y;
            acc[3][2] += a.w * b.z; acc[3][3] += a.w * b.w;
        }
        __syncthreads();
    }

    float* base = P + ((size_t)blockIdx.y * TOKENS + tok0) * E_;
    #pragma unroll
    for (int i = 0; i < 4; ++i) {
        const float4 v = make_float4(acc[i][0], acc[i][1], acc[i][2], acc[i][3]);
        *reinterpret_cast<float4*>(&base[(size_t)(t0 + i) * E_ + e0]) = v;
    }
}

// ---------------------------------------------------------------------------
// K2: reduce split-K partials; per-token softmax stats (wave per token, lane =
// expert). Writes argmax idx, gate (=max prob), accumulates probsum[b][e] and
// the z-loss directly (atomic, scaled).
// ---------------------------------------------------------------------------
__global__ __launch_bounds__(256) void k_softmax(const float* __restrict__ P,
                                                 int* __restrict__ idx,
                                                 float* __restrict__ gate,
                                                 float* __restrict__ probsum,
                                                 float* __restrict__ out_z,
                                                 int ks) {
    const int tid  = threadIdx.x;
    const int wid  = tid >> 6;
    const int lane = tid & 63;
    const int tok  = blockIdx.x * 4 + wid;

    float l = 0.f;
    for (int kc = 0; kc < ks; ++kc)
        l += P[((size_t)kc * TOKENS + tok) * E_ + lane];

    // wave argmax, first-index tie-break (matches numpy)
    float m = l; int mi = lane;
    #pragma unroll
    for (int off = 32; off > 0; off >>= 1) {
        const float om = __shfl_down(m, off);
        const int   oi = __shfl_down(mi, off);
        if (om > m || (om == m && oi < mi)) { m = om; mi = oi; }
    }
    m  = __shfl(m, 0);
    mi = __shfl(mi, 0);

    const float p = __expf(l - m);
    float s = p;
    #pragma unroll
    for (int off = 32; off > 0; off >>= 1) s += __shfl_down(s, off);
    s = __shfl(s, 0);

    __shared__ float pacc[4][E_];
    __shared__ float zv[4];
    pacc[wid][lane] = p / s;
    if (lane == 0) {
        const float lse = m + logf(s);
        zv[wid]   = lse * lse;
        idx[tok]  = mi;
        gate[tok] = 1.0f / s;                 // exp(m-m)/s = max prob
    }
    __syncthreads();

    if (tid < E_) {
        const float ps = pacc[0][tid] + pacc[1][tid] + pacc[2][tid] + pacc[3][tid];
        const int b = (blockIdx.x * 4) / N_;  // block never crosses batch
        atomicAdd(&probsum[b * E_ + tid], ps);
    }
    if (tid == 0)
        atomicAdd(out_z, (zv[0] + zv[1] + zv[2] + zv[3]) * (1.0f / (float)TOKENS));
}

// ---------------------------------------------------------------------------
// K3: ordered position-in-expert via wave ballot (matches reference cumsum),
// with the scatter into dispatch/combine and the aux-loss fused in.
// One wave per (b,e).
// ---------------------------------------------------------------------------
__global__ __launch_bounds__(64) void k_posloss(const int* __restrict__ idx,
                                                const float* __restrict__ gate,
                                                const float* __restrict__ probsum,
                                                float* __restrict__ out,
                                                float* __restrict__ out_aux,
                                                int C, size_t half) {
    const int b = blockIdx.x >> 6;
    const int e = blockIdx.x & 63;
    const int lane = threadIdx.x;
    const int*   ib = idx  + b * N_;
    const float* gb = gate + b * N_;
    float* ob = out + (size_t)b * N_ * E_ * C;   // dispatch base for batch b

    int running = 0;
    for (int step = 0; step < N_ / 64; ++step) {
        const int t = step * 64 + lane;
        const bool match = (ib[t] == e);
        const unsigned long long mask = __ballot(match);
        if (match) {
            const int p = running + __popcll(mask & ((1ull << lane) - 1ull));
            if (p < C) {
                const size_t off = (size_t)t * E_ * C + (size_t)e * C + p;
                ob[off] = 1.0f;            // dispatch
                ob[half + off] = gb[t];    // combine
            }
        }
        running += __popcll(mask);
    }
    if (lane == 0)   // aux = sum(count * probsum) * E^2/(B*E*N*N) = sum/262144
        atomicAdd(out_aux,
                  (float)running * probsum[b * E_ + e] * (1.0f / 262144.0f));
}

// ---------------------------------------------------------------------------
extern "C" void kernel_launch(void* const* d_in, const int* in_sizes, int n_in,
                              void* d_out, int out_size, void* d_ws, size_t ws_size,
                              hipStream_t stream) {
    const float* A = (const float*)d_in[0];
    const float* W = (const float*)d_in[1];
    float* out = (float*)d_out;

    const size_t half = ((size_t)out_size - 2) / 2;          // TOKENS*E*C
    const int C = (int)(half / ((size_t)TOKENS * E_));       // 40

    int ks = 8;
    auto need = [](int k) {
        return ((size_t)k * TOKENS * E_ + 2 * TOKENS + B_ * E_) * 4;
    };
    while (ks > 1 && need(ks) > ws_size) ks >>= 1;
    const int kchunk = D_ / ks;

    float* P = (float*)d_ws;
    size_t off = (size_t)ks * TOKENS * E_;
    int*   idx     = (int*)(P + off);   off += TOKENS;
    float* gate    = P + off;           off += TOKENS;
    float* probsum = P + off;           off += B_ * E_;

    float* out_aux = out + 2 * half;
    float* out_z   = out + 2 * half + 1;

    hipMemsetAsync(d_out, 0, (size_t)out_size * sizeof(float), stream);
    hipMemsetAsync(probsum, 0, B_ * E_ * sizeof(float), stream);

    k_gemm<<<dim3(TOKENS / TM, ks), 256, 0, stream>>>(A, W, P, kchunk);
    k_softmax<<<TOKENS / 4, 256, 0, stream>>>(P, idx, gate, probsum, out_z, ks);
    k_posloss<<<B_ * E_, 64, 0, stream>>>(idx, gate, probsum, out, out_aux, C, half);
}

// Round 4
// 331.319 us; speedup vs baseline: 1.0322x; 1.0322x over previous
//
#include <hip/hip_runtime.h>
#include <stdint.h>

#define B_    4
#define N_    2048
#define D_    4096
#define E_    64
#define TOKENS (B_ * N_)        // 8192
#define KT    32                // K-tile staged in LDS
#define TM    64                // tokens per block tile
#define KS    8                 // split-K factor
#define KCHUNK (D_ / KS)        // 512

typedef float vfloat4 __attribute__((ext_vector_type(4)));  // native vec for NT stores

// ---------------------------------------------------------------------------
// K1: split-K fp32 GEMM fused with d_out zero-fill.
// logits_partial[kc][tok][e] = A[tok,:]@W[:,e] over its K chunk.
// 256 threads, tile 64 tok x 64 experts, thread tile 4x4.
// Each block also streams its 10240-float4 slice of d_out as zeros
// (nontemporal), interleaved with the K-loop so the write stream hides under
// the VALU-bound FMA work. Block 0 zeroes probsum + the two loss slots.
// ---------------------------------------------------------------------------
__global__ __launch_bounds__(256) void k_gemm_z(const float* __restrict__ A,
                                                const float* __restrict__ W,
                                                float* __restrict__ P,
                                                float* __restrict__ out,
                                                float* __restrict__ probsum,
                                                float* __restrict__ losses) {
    __shared__ float As[KT][TM + 4];
    __shared__ float Ws[KT][E_ + 4];

    const int tid   = threadIdx.x;
    const int tok0  = blockIdx.x * TM;
    const int kc    = blockIdx.y;
    const int kbase = kc * KCHUNK;
    const int blin  = kc * gridDim.x + blockIdx.x;   // 0..1023

    const int t0 = (tid >> 4) * 4;       // token offset 0..60
    const int e0 = (tid & 15) * 4;       // expert offset 0..60

    const int a_kf = (tid & 7) * 4;      // k offset for A stage
    const int a_t  = tid >> 3;           // 0..31
    const int w_e  = (tid & 15) * 4;
    const int w_k  = tid >> 4;           // 0..15

    // zero-fill: block covers float4 range [blin*10240, (blin+1)*10240)
    vfloat4* zbase = reinterpret_cast<vfloat4*>(out) + (size_t)blin * 10240 + tid;
    int zstep = 0;                        // 0..39
    const vfloat4 z4 = {0.f, 0.f, 0.f, 0.f};

    if (blin == 0) {
        if (tid < B_ * E_) probsum[tid] = 0.f;
        if (tid < 2)       losses[tid]  = 0.f;
    }

    float acc[4][4] = {{0.f}};

    #pragma unroll 1
    for (int kt = 0; kt < KCHUNK; kt += KT) {
        const float* gA = A + (size_t)tok0 * D_ + (size_t)(kbase + kt);
        #pragma unroll
        for (int it = 0; it < 2; ++it) {
            const int tok = a_t + it * 32;
            const float4 v = *reinterpret_cast<const float4*>(
                gA + (size_t)tok * D_ + a_kf);
            As[a_kf + 0][tok] = v.x;
            As[a_kf + 1][tok] = v.y;
            As[a_kf + 2][tok] = v.z;
            As[a_kf + 3][tok] = v.w;
        }
        const float* gW = W + (size_t)(kbase + kt) * E_;
        #pragma unroll
        for (int it = 0; it < 2; ++it) {
            const int kk = w_k + it * 16;
            const float4 v = *reinterpret_cast<const float4*>(gW + kk * E_ + w_e);
            *reinterpret_cast<float4*>(&Ws[kk][w_e]) = v;
        }
        __syncthreads();

        // interleaved zero stores: 3/iter for first 8 iters, 2 after -> 40
        {
            const int nz = (kt < 8 * KT) ? 3 : 2;
            for (int j = 0; j < nz; ++j) {
                __builtin_nontemporal_store(z4, zbase + (size_t)zstep * 256);
                ++zstep;
            }
        }

        #pragma unroll
        for (int kk = 0; kk < KT; ++kk) {
            const float4 a = *reinterpret_cast<const float4*>(&As[kk][t0]);
            const float4 b = *reinterpret_cast<const float4*>(&Ws[kk][e0]);
            acc[0][0] += a.x * b.x; acc[0][1] += a.x * b.y;
            acc[0][2] += a.x * b.z; acc[0][3] += a.x * b.w;
            acc[1][0] += a.y * b.x; acc[1][1] += a.y * b.y;
            acc[1][2] += a.y * b.z; acc[1][3] += a.y * b.w;
            acc[2][0] += a.z * b.x; acc[2][1] += a.z * b.y;
            acc[2][2] += a.z * b.z; acc[2][3] += a.z * b.w;
            acc[3][0] += a.w * b.x; acc[3][1] += a.w * b.y;
            acc[3][2] += a.w * b.z; acc[3][3] += a.w * b.w;
        }
        __syncthreads();
    }

    float* base = P + ((size_t)kc * TOKENS + tok0) * E_;
    #pragma unroll
    for (int i = 0; i < 4; ++i) {
        const float4 v = make_float4(acc[i][0], acc[i][1], acc[i][2], acc[i][3]);
        *reinterpret_cast<float4*>(&base[(size_t)(t0 + i) * E_ + e0]) = v;
    }
}

// ---------------------------------------------------------------------------
// K2: reduce split-K partials; per-token softmax stats (wave per token, lane =
// expert). Writes argmax idx, gate (=max prob), accumulates probsum[b][e] and
// the z-loss (atomic, pre-scaled).
// ---------------------------------------------------------------------------
__global__ __launch_bounds__(256) void k_softmax(const float* __restrict__ P,
                                                 int* __restrict__ idx,
                                                 float* __restrict__ gate,
                                                 float* __restrict__ probsum,
                                                 float* __restrict__ out_z) {
    const int tid  = threadIdx.x;
    const int wid  = tid >> 6;
    const int lane = tid & 63;
    const int tok  = blockIdx.x * 4 + wid;

    float l = 0.f;
    #pragma unroll
    for (int kc = 0; kc < KS; ++kc)
        l += P[((size_t)kc * TOKENS + tok) * E_ + lane];

    // wave argmax, first-index tie-break (matches numpy)
    float m = l; int mi = lane;
    #pragma unroll
    for (int off = 32; off > 0; off >>= 1) {
        const float om = __shfl_down(m, off);
        const int   oi = __shfl_down(mi, off);
        if (om > m || (om == m && oi < mi)) { m = om; mi = oi; }
    }
    m  = __shfl(m, 0);
    mi = __shfl(mi, 0);

    const float p = __expf(l - m);
    float s = p;
    #pragma unroll
    for (int off = 32; off > 0; off >>= 1) s += __shfl_down(s, off);
    s = __shfl(s, 0);

    __shared__ float pacc[4][E_];
    __shared__ float zv[4];
    pacc[wid][lane] = p / s;
    if (lane == 0) {
        const float lse = m + logf(s);
        zv[wid]   = lse * lse;
        idx[tok]  = mi;
        gate[tok] = 1.0f / s;                 // exp(m-m)/s = max prob
    }
    __syncthreads();

    if (tid < E_) {
        const float ps = pacc[0][tid] + pacc[1][tid] + pacc[2][tid] + pacc[3][tid];
        const int b = (blockIdx.x * 4) / N_;  // block never crosses batch
        atomicAdd(&probsum[b * E_ + tid], ps);
    }
    if (tid == 0)
        atomicAdd(out_z, (zv[0] + zv[1] + zv[2] + zv[3]) * (1.0f / (float)TOKENS));
}

// ---------------------------------------------------------------------------
// K3: ordered position-in-expert via wave ballot (matches reference cumsum),
// scatter into dispatch/combine + aux-loss fused. One wave per (b,e).
// ---------------------------------------------------------------------------
__global__ __launch_bounds__(64) void k_posloss(const int* __restrict__ idx,
                                                const float* __restrict__ gate,
                                                const float* __restrict__ probsum,
                                                float* __restrict__ out,
                                                float* __restrict__ out_aux,
                                                int C, size_t half) {
    const int b = blockIdx.x >> 6;
    const int e = blockIdx.x & 63;
    const int lane = threadIdx.x;
    const int*   ib = idx  + b * N_;
    const float* gb = gate + b * N_;
    float* ob = out + (size_t)b * N_ * E_ * C;   // dispatch base for batch b

    int running = 0;
    for (int step = 0; step < N_ / 64; ++step) {
        const int t = step * 64 + lane;
        const bool match = (ib[t] == e);
        const unsigned long long mask = __ballot(match);
        if (match) {
            const int p = running + __popcll(mask & ((1ull << lane) - 1ull));
            if (p < C) {
                const size_t off = (size_t)t * E_ * C + (size_t)e * C + p;
                ob[off] = 1.0f;            // dispatch
                ob[half + off] = gb[t];    // combine
            }
        }
        running += __popcll(mask);
    }
    if (lane == 0)   // aux = sum(count * probsum) * E^2/(B*E*N*N) = sum/262144
        atomicAdd(out_aux,
                  (float)running * probsum[b * E_ + e] * (1.0f / 262144.0f));
}

// ---------------------------------------------------------------------------
extern "C" void kernel_launch(void* const* d_in, const int* in_sizes, int n_in,
                              void* d_out, int out_size, void* d_ws, size_t ws_size,
                              hipStream_t stream) {
    const float* A = (const float*)d_in[0];
    const float* W = (const float*)d_in[1];
    float* out = (float*)d_out;

    const size_t half = ((size_t)out_size - 2) / 2;          // TOKENS*E*C
    const int C = (int)(half / ((size_t)TOKENS * E_));       // 40

    float* P = (float*)d_ws;
    size_t off = (size_t)KS * TOKENS * E_;
    int*   idx     = (int*)(P + off);   off += TOKENS;
    float* gate    = P + off;           off += TOKENS;
    float* probsum = P + off;           off += B_ * E_;

    float* out_aux = out + 2 * half;
    float* out_z   = out + 2 * half + 1;

    // k_gemm_z zeroes all of d_out (2*half floats via per-block NT-store
    // slices; 2*half = 41,943,040 floats = 1024 blocks * 10240 float4 exactly)
    // plus probsum and the two loss scalars (block 0). No hipMemsetAsync.
    k_gemm_z<<<dim3(TOKENS / TM, KS), 256, 0, stream>>>(A, W, P, out, probsum,
                                                        out_aux);
    k_softmax<<<TOKENS / 4, 256, 0, stream>>>(P, idx, gate, probsum, out_z);
    k_posloss<<<B_ * E_, 64, 0, stream>>>(idx, gate, probsum, out, out_aux, C, half);
}